// Round 12
// baseline (1161.209 us; speedup 1.0000x reference)
//
#include <hip/hip_runtime.h>

// RVQ, MI355X round 12: fused 4-layer kernel, q-loop FULLY UNROLLED to give
// the register allocator straight-line code (r8-proven shape; r10/r11's
// loop-carried rv4/rh spilled to scratch: symmetric ~500MB excess F/W).
// 16 rows/wave fp32 in regs; per layer: MFMA screen (hi-fp16, u32-key top-4)
// -> np-fp32 re-rank of near-ties -> in-register exact residual update.
// Final: out = x - r_final via LDS transpose -> full-line stores.
// ws: [0,2MB) hi frags f16 [4][64 ct][8 j][64 lane][8]
//     [2MB,+16KB) e2b = sum(e^2)+512 ; then f64 loss[4]

#define NUM_Q   4
#define KCODE   1024
#define DIM     256
#define NROWS   131072
#define QELEMS  33554432
#define MARGIN_FLAG 0.40f
#define KMASK   0xFFFFFC00u

typedef _Float16 f16x8 __attribute__((ext_vector_type(8)));
typedef float    f32x4 __attribute__((ext_vector_type(4)));

__device__ __forceinline__ float dqk(unsigned k) { return __uint_as_float(k & KMASK); }
__device__ __forceinline__ unsigned umin2(unsigned a, unsigned b) { return a < b ? a : b; }
__device__ __forceinline__ unsigned umax2(unsigned a, unsigned b) { return a > b ? a : b; }

// ---------------------------------------------------------------- prep
__global__ __launch_bounds__(64) void rvq_prep(const float* __restrict__ emb,
                                               _Float16* __restrict__ efrag,
                                               float* __restrict__ e2b,
                                               double* __restrict__ loss)
{
    const int bid  = blockIdx.x;            // layer*64 + ct
    const int lane = threadIdx.x;
    const int layer = bid >> 6;
    const int c = (bid & 63)*16 + (lane & 15);
    const int g = lane >> 4;
    const float* ep = emb + ((size_t)layer*KCODE + c)*DIM;

    double s2 = 0.0;
    #pragma unroll
    for (int j = 0; j < 8; ++j) {
        const int k0 = j*32 + 8*g;
        float4 a = *(const float4*)(ep + k0);
        float4 b = *(const float4*)(ep + k0 + 4);
        float v[8] = {a.x,a.y,a.z,a.w,b.x,b.y,b.z,b.w};
        f16x8 hh;
        #pragma unroll
        for (int x = 0; x < 8; ++x) {
            double dv = (double)v[x];
            s2 += dv*dv;
            hh[x] = (_Float16)(-2.0f*v[x]);          // fold -2 exactly
        }
        *(f16x8*)(efrag + ((size_t)(bid*8 + j)*64 + lane)*8) = hh;
    }
    s2 += __shfl_xor(s2, 16);
    s2 += __shfl_xor(s2, 32);
    if (g == 0) e2b[layer*KCODE + c] = (float)(s2 + 512.0);  // bias keeps keys positive
    if (bid == 0 && lane < 4) loss[lane] = 0.0;
}

// ------------- bit-exact numpy fp32 distance (validated r4-r11) -------------
__device__ __forceinline__ float np_sq128(const float* p) {
    #pragma clang fp contract(off)
    float s[16], U[4];
    #pragma unroll
    for (int l = 0; l < 16; ++l) {
        s[l] = ((p[l]*p[l] + p[16+l]*p[16+l]) + (p[32+l]*p[32+l] + p[48+l]*p[48+l]))
             + ((p[64+l]*p[64+l] + p[80+l]*p[80+l]) + (p[96+l]*p[96+l] + p[112+l]*p[112+l]));
    }
    #pragma unroll
    for (int i = 0; i < 4; ++i) U[i] = (s[i] + s[i+8]) + (s[i+4] + s[i+12]);
    return (U[0] + U[2]) + (U[1] + U[3]);
}
__device__ __forceinline__ float np_dist(const float* rp, const float* ep) {
    #pragma clang fp contract(off)
    float m = 0.f;
    #pragma unroll
    for (int kb = 0; kb < 16; ++kb) {          // batched loads, exact FMA order
        float a[16];
        #pragma unroll
        for (int x = 0; x < 4; ++x) {
            float4 v = *(const float4*)(ep + kb*16 + x*4);
            a[x*4+0]=v.x; a[x*4+1]=v.y; a[x*4+2]=v.z; a[x*4+3]=v.w;
        }
        #pragma unroll
        for (int x = 0; x < 16; ++x) m = __builtin_fmaf(rp[kb*16+x], a[x], m);
    }
    float se = np_sq128(ep) + np_sq128(ep + 128);
    float sr = np_sq128(rp) + np_sq128(rp + 128);
    return (sr + se) - 2.0f*m;
}

// ---------------------------------------------------------------- fused
__global__ __launch_bounds__(256, 2) void rvq_fused(
    const float* __restrict__ x, float* __restrict__ out,
    const float* __restrict__ emb,        // [4][1024][256]
    const _Float16* __restrict__ efrag,   // [4][64][8][64][8]
    const float* __restrict__ e2b,        // [4][1024] (biased +512)
    float* __restrict__ idx_base,         // [4][NROWS] as float
    double* __restrict__ loss)            // [4] (we add into [0])
{
    __shared__ __align__(16) _Float16 lt[2][8][64][8];   // 16 KB dbuf
    __shared__ __align__(16) float    e2l[NUM_Q*KCODE];  // 16 KB (all layers)
    __shared__ __align__(16) float    s_remu[4][DIM];    // 4 KB
    __shared__ __align__(16) float    stg[4][4][260];    // 16.6 KB transpose staging
    __shared__ double wsum[4];

    const int tid  = threadIdx.x;
    const int w    = tid >> 6;
    const int lane = tid & 63;
    const int col  = lane & 15;
    const int g    = lane >> 4;
    const int r0   = blockIdx.x*64 + w*16;    // 16 rows per wave

    // load rows from x -> fp32 regs (64 VGPR) + hi-fp16 fragments (32 VGPR)
    f32x4 rv4[16];
    f16x8 rh[8];
    {
        const float* rp = x + (size_t)(r0 + col)*DIM + 8*g;
        #pragma unroll
        for (int j = 0; j < 8; ++j) {
            rv4[2*j]   = *(const f32x4*)(rp + j*32);
            rv4[2*j+1] = *(const f32x4*)(rp + j*32 + 4);
            #pragma unroll
            for (int xx = 0; xx < 4; ++xx) {
                rh[j][xx]   = (_Float16)rv4[2*j][xx];
                rh[j][4+xx] = (_Float16)rv4[2*j+1][xx];
            }
        }
    }

    // stage ALL layers' e2 once (16 KB)
    {
        #pragma unroll
        for (int b = 0; b < 4; ++b)
            *(f32x4*)(e2l + b*1024 + tid*4) = *(const f32x4*)(e2b + b*1024 + tid*4);
    }

    const uint4* gsrc = (const uint4*)efrag;     // 512 uint4 per 8KB tile
    double lacc = 0.0;                           // total sum of squares, all layers

    #pragma unroll
    for (int q = 0; q < NUM_Q; ++q) {
        const float* embq = emb + (size_t)q*KCODE*DIM;

        // stage tile 0 for this layer
        {
            const uint4* gt = gsrc + (size_t)q*64*512;
            uint4 s0 = gt[tid], s1 = gt[256 + tid];
            uint4* lw = (uint4*)&lt[0][0][0][0];
            lw[tid] = s0; lw[256 + tid] = s1;
        }
        __syncthreads();

        unsigned k1 = ~0u, k2 = ~0u, k3 = ~0u, k4 = ~0u;
        const unsigned kor = (unsigned)(g << 2);

        for (int ct = 0; ct < 64; ++ct) {
            const int cur = ct & 1;
            uint4 p0, p1;
            if (ct < 63) {                       // prefetch next tile to regs
                const uint4* gt = gsrc + ((size_t)q*64 + ct + 1)*512;
                p0 = gt[tid]; p1 = gt[256 + tid];
            }
            f32x4 acc = *(const f32x4*)(e2l + q*KCODE + ct*16 + 4*g);  // C = e2+512
            #pragma unroll
            for (int j = 0; j < 8; ++j) {
                f16x8 ah = *(const f16x8*)&lt[cur][j][lane][0];
                acc = __builtin_amdgcn_mfma_f32_16x16x32_f16(ah, rh[j], acc, 0,0,0);
            }
            const unsigned ctb = (unsigned)(ct << 4);
            #pragma unroll
            for (int r = 0; r < 4; ++r) {
                unsigned key = (__float_as_uint(acc[r]) & KMASK) | kor | (ctb + (unsigned)r);
                unsigned a1 = umin2(k1, key), b1 = umax2(k1, key); k1 = a1;
                unsigned a2 = umin2(k2, b1),  b2 = umax2(k2, b1);  k2 = a2;
                unsigned a3 = umin2(k3, b2),  b3 = umax2(k3, b2);  k3 = a3;
                k4 = umin2(k4, b3);
            }
            if (ct < 63) {
                uint4* lw = (uint4*)&lt[cur^1][0][0][0];
                lw[tid] = p0; lw[256 + tid] = p1;
            }
            __syncthreads();
        }

        // per-row min, flags, re-rank (staged from regs), index write
        int fidx;
        {
            unsigned gm = k1;
            gm = umin2(gm, __shfl_xor(gm, 16));
            gm = umin2(gm, __shfl_xor(gm, 32));
            float thr = dqk(gm) + MARGIN_FLAG;
            bool c1 = (k1 != gm) && (dqk(k1) < thr);
            bool c2 = dqk(k2) < thr;
            bool c3 = dqk(k3) < thr;
            bool c4 = dqk(k4) < thr;
            unsigned long long b = __ballot(c1 || c2 || c3 || c4);
            unsigned rowm = (unsigned)((b | (b>>16) | (b>>32) | (b>>48)) & 0xFFFFull);
            fidx = (int)(gm & 1023u);

            unsigned m = rowm;
            while (m) {
                int p = __ffs(m) - 1; m &= m - 1;
                if (col == p) {                  // stage row p to LDS from regs
                    #pragma unroll
                    for (int j = 0; j < 8; ++j) {
                        *(f32x4*)&s_remu[w][j*32 + 8*g]     = rv4[2*j];
                        *(f32x4*)&s_remu[w][j*32 + 8*g + 4] = rv4[2*j+1];
                    }
                }
                asm volatile("s_waitcnt lgkmcnt(0)" ::: "memory");
                int srcl = ((lane & 12) << 2) | p;          // 16 eval lanes
                unsigned s1 = __shfl(k1, srcl), s2 = __shfl(k2, srcl);
                unsigned s3 = __shfl(k3, srcl), s4 = __shfl(k4, srcl);
                int slot = lane & 3;
                unsigned ksel = slot == 0 ? s1 : (slot == 1 ? s2 : (slot == 2 ? s3 : s4));
                float thr_p = __shfl(thr, p);
                bool valid = (lane < 16) && (dqk(ksel) < thr_p);
                float d = 3.4e38f;
                int   cc = 0x7FFFFFFF;
                if (valid) {
                    cc = (int)(ksel & 1023u);
                    d  = np_dist(&s_remu[w][0], embq + (size_t)cc*DIM);
                }
                #pragma unroll
                for (int off = 1; off < 64; off <<= 1) {
                    float od = __shfl_xor(d, off);
                    int   oc = __shfl_xor(cc, off);
                    if (od < d || (od == d && oc < cc)) { d = od; cc = oc; }
                }
                if (col == p) fidx = cc;
            }
            if (lane < 16) idx_base[(size_t)q*NROWS + r0 + lane] = (float)fidx;
        }

        // in-register residual update (exact fp32 3-op chain) + running loss
        {
            const float* ep = embq + (size_t)fidx*DIM + 8*g;
            #pragma unroll
            for (int j = 0; j < 8; ++j) {
                #pragma clang fp contract(off)
                f32x4 e0 = *(const f32x4*)(ep + j*32);
                f32x4 e1 = *(const f32x4*)(ep + j*32 + 4);
                #pragma unroll
                for (int xx = 0; xx < 4; ++xx) {
                    float r1 = rv4[2*j][xx];
                    float tq1 = e0[xx] - r1;
                    float qs1 = r1 + tq1;
                    rv4[2*j][xx] = r1 - qs1;
                    lacc += (double)tq1 * (double)tq1;
                    float r2 = rv4[2*j+1][xx];
                    float tq2 = e1[xx] - r2;
                    float qs2 = r2 + tq2;
                    rv4[2*j+1][xx] = r2 - qs2;
                    lacc += (double)tq2 * (double)tq2;
                }
                #pragma unroll
                for (int xx = 0; xx < 4; ++xx) {
                    rh[j][xx]   = (_Float16)rv4[2*j][xx];
                    rh[j][4+xx] = (_Float16)rv4[2*j+1][xx];
                }
            }
        }
    }

    // one loss reduction for all layers
    #pragma unroll
    for (int o = 32; o; o >>= 1) lacc += __shfl_xor(lacc, o);
    if (lane == 0) wsum[w] = lacc;
    __syncthreads();
    if (tid == 0) atomicAdd(loss, wsum[0]+wsum[1]+wsum[2]+wsum[3]);

    // final: out = x - r_final. LDS transpose (frag layout -> row layout),
    // full-1KB-line coalesced x reads and out stores (no write-allocate).
    for (int c = 0; c < 4; ++c) {
        if ((col >> 2) == c) {                   // 16 active lanes: 4 rows x 4 g
            #pragma unroll
            for (int j = 0; j < 8; ++j) {
                *(f32x4*)&stg[w][col & 3][j*32 + 8*g]     = rv4[2*j];
                *(f32x4*)&stg[w][col & 3][j*32 + 8*g + 4] = rv4[2*j+1];
            }
        }
        asm volatile("s_waitcnt lgkmcnt(0)" ::: "memory");
        #pragma unroll
        for (int k = 0; k < 4; ++k) {
            int row = r0 + 4*c + k;
            f32x4 rf = *(const f32x4*)&stg[w][k][4*lane];
            f32x4 xv = *(const f32x4*)(x + (size_t)row*DIM + 4*lane);
            f32x4 ov;
            #pragma unroll
            for (int xx = 0; xx < 4; ++xx) ov[xx] = xv[xx] - rf[xx];
            *(f32x4*)(out + (size_t)row*DIM + 4*lane) = ov;
        }
        asm volatile("s_waitcnt lgkmcnt(0)" ::: "memory");  // drain reads before re-stage
    }
}

// ---------------------------------------------------------------- loss finalize
__global__ void rvq_loss(const double* __restrict__ loss, float* __restrict__ lossout)
{
    double tot = (loss[0]+loss[1]+loss[2]+loss[3]) * (1.0/(double)QELEMS);
    lossout[0] = (float)(1.25*tot);
    lossout[1] = (float)(0.25*tot);
    lossout[2] = (float)tot;
}

// ---------------------------------------------------------------- launch
extern "C" void kernel_launch(void* const* d_in, const int* in_sizes, int n_in,
                              void* d_out, int out_size, void* d_ws, size_t ws_size,
                              hipStream_t stream)
{
    (void)in_sizes; (void)n_in; (void)out_size; (void)ws_size;
    const float* x   = (const float*)d_in[0];
    const float* emb = (const float*)d_in[1];
    float* out      = (float*)d_out;
    float* idx_base = out + QELEMS;
    float* loss_out = out + QELEMS + (size_t)NUM_Q*NROWS;

    _Float16* efrag = (_Float16*)d_ws;                              // 2 MB
    float*    e2b   = (float*)((char*)d_ws + 2u*1024u*1024u);       // 16 KB
    double*   loss  = (double*)((char*)d_ws + 2u*1024u*1024u + 16384u);

    rvq_prep<<<NUM_Q*64, 64, 0, stream>>>(emb, efrag, e2b, loss);
    rvq_fused<<<NROWS/64, 256, 0, stream>>>(x, out, emb, efrag, e2b, idx_base, loss);
    rvq_loss<<<1, 1, 0, stream>>>(loss, loss_out);
}

// Round 13
// 871.336 us; speedup vs baseline: 1.3327x; 1.3327x over previous
//
#include <hip/hip_runtime.h>

// RVQ, MI355X round 13: r12 fused kernel + amdgpu_waves_per_eu(2,2) to pin
// the register allocator's budget at 256 VGPR (r10-r12 all emitted exactly
// 128 VGPR and spilled ~1.5KB/thread: the allocator's 4-waves/EU occupancy
// heuristic, not code shape, was the cap). Occupancy target unchanged vs r4
// (8 waves/CU). Everything else identical to r12.
// ws: [0,2MB) hi frags f16 [4][64 ct][8 j][64 lane][8]
//     [2MB,+16KB) e2b = sum(e^2)+512 ; then f64 loss[4]

#define NUM_Q   4
#define KCODE   1024
#define DIM     256
#define NROWS   131072
#define QELEMS  33554432
#define MARGIN_FLAG 0.40f
#define KMASK   0xFFFFFC00u

typedef _Float16 f16x8 __attribute__((ext_vector_type(8)));
typedef float    f32x4 __attribute__((ext_vector_type(4)));

__device__ __forceinline__ float dqk(unsigned k) { return __uint_as_float(k & KMASK); }
__device__ __forceinline__ unsigned umin2(unsigned a, unsigned b) { return a < b ? a : b; }
__device__ __forceinline__ unsigned umax2(unsigned a, unsigned b) { return a > b ? a : b; }

// ---------------------------------------------------------------- prep
__global__ __launch_bounds__(64) void rvq_prep(const float* __restrict__ emb,
                                               _Float16* __restrict__ efrag,
                                               float* __restrict__ e2b,
                                               double* __restrict__ loss)
{
    const int bid  = blockIdx.x;            // layer*64 + ct
    const int lane = threadIdx.x;
    const int layer = bid >> 6;
    const int c = (bid & 63)*16 + (lane & 15);
    const int g = lane >> 4;
    const float* ep = emb + ((size_t)layer*KCODE + c)*DIM;

    double s2 = 0.0;
    #pragma unroll
    for (int j = 0; j < 8; ++j) {
        const int k0 = j*32 + 8*g;
        float4 a = *(const float4*)(ep + k0);
        float4 b = *(const float4*)(ep + k0 + 4);
        float v[8] = {a.x,a.y,a.z,a.w,b.x,b.y,b.z,b.w};
        f16x8 hh;
        #pragma unroll
        for (int x = 0; x < 8; ++x) {
            double dv = (double)v[x];
            s2 += dv*dv;
            hh[x] = (_Float16)(-2.0f*v[x]);          // fold -2 exactly
        }
        *(f16x8*)(efrag + ((size_t)(bid*8 + j)*64 + lane)*8) = hh;
    }
    s2 += __shfl_xor(s2, 16);
    s2 += __shfl_xor(s2, 32);
    if (g == 0) e2b[layer*KCODE + c] = (float)(s2 + 512.0);  // bias keeps keys positive
    if (bid == 0 && lane < 4) loss[lane] = 0.0;
}

// ------------- bit-exact numpy fp32 distance (validated r4-r12) -------------
__device__ __forceinline__ float np_sq128(const float* p) {
    #pragma clang fp contract(off)
    float s[16], U[4];
    #pragma unroll
    for (int l = 0; l < 16; ++l) {
        s[l] = ((p[l]*p[l] + p[16+l]*p[16+l]) + (p[32+l]*p[32+l] + p[48+l]*p[48+l]))
             + ((p[64+l]*p[64+l] + p[80+l]*p[80+l]) + (p[96+l]*p[96+l] + p[112+l]*p[112+l]));
    }
    #pragma unroll
    for (int i = 0; i < 4; ++i) U[i] = (s[i] + s[i+8]) + (s[i+4] + s[i+12]);
    return (U[0] + U[2]) + (U[1] + U[3]);
}
__device__ __forceinline__ float np_dist(const float* rp, const float* ep) {
    #pragma clang fp contract(off)
    float m = 0.f;
    #pragma unroll
    for (int kb = 0; kb < 16; ++kb) {          // batched loads, exact FMA order
        float a[16];
        #pragma unroll
        for (int x = 0; x < 4; ++x) {
            float4 v = *(const float4*)(ep + kb*16 + x*4);
            a[x*4+0]=v.x; a[x*4+1]=v.y; a[x*4+2]=v.z; a[x*4+3]=v.w;
        }
        #pragma unroll
        for (int x = 0; x < 16; ++x) m = __builtin_fmaf(rp[kb*16+x], a[x], m);
    }
    float se = np_sq128(ep) + np_sq128(ep + 128);
    float sr = np_sq128(rp) + np_sq128(rp + 128);
    return (sr + se) - 2.0f*m;
}

// ---------------------------------------------------------------- fused
__global__ __launch_bounds__(256)
__attribute__((amdgpu_waves_per_eu(2, 2)))
void rvq_fused(
    const float* __restrict__ x, float* __restrict__ out,
    const float* __restrict__ emb,        // [4][1024][256]
    const _Float16* __restrict__ efrag,   // [4][64][8][64][8]
    const float* __restrict__ e2b,        // [4][1024] (biased +512)
    float* __restrict__ idx_base,         // [4][NROWS] as float
    double* __restrict__ loss)            // [4] (we add into [0])
{
    __shared__ __align__(16) _Float16 lt[2][8][64][8];   // 16 KB dbuf
    __shared__ __align__(16) float    e2l[NUM_Q*KCODE];  // 16 KB (all layers)
    __shared__ __align__(16) float    s_remu[4][DIM];    // 4 KB
    __shared__ __align__(16) float    stg[4][4][260];    // 16.6 KB transpose staging
    __shared__ double wsum[4];

    const int tid  = threadIdx.x;
    const int w    = tid >> 6;
    const int lane = tid & 63;
    const int col  = lane & 15;
    const int g    = lane >> 4;
    const int r0   = blockIdx.x*64 + w*16;    // 16 rows per wave

    // load rows from x -> fp32 regs (64 VGPR) + hi-fp16 fragments (32 VGPR)
    f32x4 rv4[16];
    f16x8 rh[8];
    {
        const float* rp = x + (size_t)(r0 + col)*DIM + 8*g;
        #pragma unroll
        for (int j = 0; j < 8; ++j) {
            rv4[2*j]   = *(const f32x4*)(rp + j*32);
            rv4[2*j+1] = *(const f32x4*)(rp + j*32 + 4);
            #pragma unroll
            for (int xx = 0; xx < 4; ++xx) {
                rh[j][xx]   = (_Float16)rv4[2*j][xx];
                rh[j][4+xx] = (_Float16)rv4[2*j+1][xx];
            }
        }
    }

    // stage ALL layers' e2 once (16 KB)
    {
        #pragma unroll
        for (int b = 0; b < 4; ++b)
            *(f32x4*)(e2l + b*1024 + tid*4) = *(const f32x4*)(e2b + b*1024 + tid*4);
    }

    const uint4* gsrc = (const uint4*)efrag;     // 512 uint4 per 8KB tile
    double lacc = 0.0;                           // total sum of squares, all layers

    #pragma unroll
    for (int q = 0; q < NUM_Q; ++q) {
        const float* embq = emb + (size_t)q*KCODE*DIM;

        // stage tile 0 for this layer
        {
            const uint4* gt = gsrc + (size_t)q*64*512;
            uint4 s0 = gt[tid], s1 = gt[256 + tid];
            uint4* lw = (uint4*)&lt[0][0][0][0];
            lw[tid] = s0; lw[256 + tid] = s1;
        }
        __syncthreads();

        unsigned k1 = ~0u, k2 = ~0u, k3 = ~0u, k4 = ~0u;
        const unsigned kor = (unsigned)(g << 2);

        for (int ct = 0; ct < 64; ++ct) {
            const int cur = ct & 1;
            uint4 p0, p1;
            if (ct < 63) {                       // prefetch next tile to regs
                const uint4* gt = gsrc + ((size_t)q*64 + ct + 1)*512;
                p0 = gt[tid]; p1 = gt[256 + tid];
            }
            f32x4 acc = *(const f32x4*)(e2l + q*KCODE + ct*16 + 4*g);  // C = e2+512
            #pragma unroll
            for (int j = 0; j < 8; ++j) {
                f16x8 ah = *(const f16x8*)&lt[cur][j][lane][0];
                acc = __builtin_amdgcn_mfma_f32_16x16x32_f16(ah, rh[j], acc, 0,0,0);
            }
            const unsigned ctb = (unsigned)(ct << 4);
            #pragma unroll
            for (int r = 0; r < 4; ++r) {
                unsigned key = (__float_as_uint(acc[r]) & KMASK) | kor | (ctb + (unsigned)r);
                unsigned a1 = umin2(k1, key), b1 = umax2(k1, key); k1 = a1;
                unsigned a2 = umin2(k2, b1),  b2 = umax2(k2, b1);  k2 = a2;
                unsigned a3 = umin2(k3, b2),  b3 = umax2(k3, b2);  k3 = a3;
                k4 = umin2(k4, b3);
            }
            if (ct < 63) {
                uint4* lw = (uint4*)&lt[cur^1][0][0][0];
                lw[tid] = p0; lw[256 + tid] = p1;
            }
            __syncthreads();
        }

        // per-row min, flags, re-rank (staged from regs), index write
        int fidx;
        {
            unsigned gm = k1;
            gm = umin2(gm, __shfl_xor(gm, 16));
            gm = umin2(gm, __shfl_xor(gm, 32));
            float thr = dqk(gm) + MARGIN_FLAG;
            bool c1 = (k1 != gm) && (dqk(k1) < thr);
            bool c2 = dqk(k2) < thr;
            bool c3 = dqk(k3) < thr;
            bool c4 = dqk(k4) < thr;
            unsigned long long b = __ballot(c1 || c2 || c3 || c4);
            unsigned rowm = (unsigned)((b | (b>>16) | (b>>32) | (b>>48)) & 0xFFFFull);
            fidx = (int)(gm & 1023u);

            unsigned m = rowm;
            while (m) {
                int p = __ffs(m) - 1; m &= m - 1;
                if (col == p) {                  // stage row p to LDS from regs
                    #pragma unroll
                    for (int j = 0; j < 8; ++j) {
                        *(f32x4*)&s_remu[w][j*32 + 8*g]     = rv4[2*j];
                        *(f32x4*)&s_remu[w][j*32 + 8*g + 4] = rv4[2*j+1];
                    }
                }
                asm volatile("s_waitcnt lgkmcnt(0)" ::: "memory");
                int srcl = ((lane & 12) << 2) | p;          // 16 eval lanes
                unsigned s1 = __shfl(k1, srcl), s2 = __shfl(k2, srcl);
                unsigned s3 = __shfl(k3, srcl), s4 = __shfl(k4, srcl);
                int slot = lane & 3;
                unsigned ksel = slot == 0 ? s1 : (slot == 1 ? s2 : (slot == 2 ? s3 : s4));
                float thr_p = __shfl(thr, p);
                bool valid = (lane < 16) && (dqk(ksel) < thr_p);
                float d = 3.4e38f;
                int   cc = 0x7FFFFFFF;
                if (valid) {
                    cc = (int)(ksel & 1023u);
                    d  = np_dist(&s_remu[w][0], embq + (size_t)cc*DIM);
                }
                #pragma unroll
                for (int off = 1; off < 64; off <<= 1) {
                    float od = __shfl_xor(d, off);
                    int   oc = __shfl_xor(cc, off);
                    if (od < d || (od == d && oc < cc)) { d = od; cc = oc; }
                }
                if (col == p) fidx = cc;
            }
            if (lane < 16) idx_base[(size_t)q*NROWS + r0 + lane] = (float)fidx;
        }

        // in-register residual update (exact fp32 3-op chain) + running loss
        {
            const float* ep = embq + (size_t)fidx*DIM + 8*g;
            #pragma unroll
            for (int j = 0; j < 8; ++j) {
                #pragma clang fp contract(off)
                f32x4 e0 = *(const f32x4*)(ep + j*32);
                f32x4 e1 = *(const f32x4*)(ep + j*32 + 4);
                #pragma unroll
                for (int xx = 0; xx < 4; ++xx) {
                    float r1 = rv4[2*j][xx];
                    float tq1 = e0[xx] - r1;
                    float qs1 = r1 + tq1;
                    rv4[2*j][xx] = r1 - qs1;
                    lacc += (double)tq1 * (double)tq1;
                    float r2 = rv4[2*j+1][xx];
                    float tq2 = e1[xx] - r2;
                    float qs2 = r2 + tq2;
                    rv4[2*j+1][xx] = r2 - qs2;
                    lacc += (double)tq2 * (double)tq2;
                }
                #pragma unroll
                for (int xx = 0; xx < 4; ++xx) {
                    rh[j][xx]   = (_Float16)rv4[2*j][xx];
                    rh[j][4+xx] = (_Float16)rv4[2*j+1][xx];
                }
            }
        }
    }

    // one loss reduction for all layers
    #pragma unroll
    for (int o = 32; o; o >>= 1) lacc += __shfl_xor(lacc, o);
    if (lane == 0) wsum[w] = lacc;
    __syncthreads();
    if (tid == 0) atomicAdd(loss, wsum[0]+wsum[1]+wsum[2]+wsum[3]);

    // final: out = x - r_final. LDS transpose (frag layout -> row layout),
    // full-1KB-line coalesced x reads and out stores (no write-allocate).
    for (int c = 0; c < 4; ++c) {
        if ((col >> 2) == c) {                   // 16 active lanes: 4 rows x 4 g
            #pragma unroll
            for (int j = 0; j < 8; ++j) {
                *(f32x4*)&stg[w][col & 3][j*32 + 8*g]     = rv4[2*j];
                *(f32x4*)&stg[w][col & 3][j*32 + 8*g + 4] = rv4[2*j+1];
            }
        }
        asm volatile("s_waitcnt lgkmcnt(0)" ::: "memory");
        #pragma unroll
        for (int k = 0; k < 4; ++k) {
            int row = r0 + 4*c + k;
            f32x4 rf = *(const f32x4*)&stg[w][k][4*lane];
            f32x4 xv = *(const f32x4*)(x + (size_t)row*DIM + 4*lane);
            f32x4 ov;
            #pragma unroll
            for (int xx = 0; xx < 4; ++xx) ov[xx] = xv[xx] - rf[xx];
            *(f32x4*)(out + (size_t)row*DIM + 4*lane) = ov;
        }
        asm volatile("s_waitcnt lgkmcnt(0)" ::: "memory");  // drain reads before re-stage
    }
}

// ---------------------------------------------------------------- loss finalize
__global__ void rvq_loss(const double* __restrict__ loss, float* __restrict__ lossout)
{
    double tot = (loss[0]+loss[1]+loss[2]+loss[3]) * (1.0/(double)QELEMS);
    lossout[0] = (float)(1.25*tot);
    lossout[1] = (float)(0.25*tot);
    lossout[2] = (float)tot;
}

// ---------------------------------------------------------------- launch
extern "C" void kernel_launch(void* const* d_in, const int* in_sizes, int n_in,
                              void* d_out, int out_size, void* d_ws, size_t ws_size,
                              hipStream_t stream)
{
    (void)in_sizes; (void)n_in; (void)out_size; (void)ws_size;
    const float* x   = (const float*)d_in[0];
    const float* emb = (const float*)d_in[1];
    float* out      = (float*)d_out;
    float* idx_base = out + QELEMS;
    float* loss_out = out + QELEMS + (size_t)NUM_Q*NROWS;

    _Float16* efrag = (_Float16*)d_ws;                              // 2 MB
    float*    e2b   = (float*)((char*)d_ws + 2u*1024u*1024u);       // 16 KB
    double*   loss  = (double*)((char*)d_ws + 2u*1024u*1024u + 16384u);

    rvq_prep<<<NUM_Q*64, 64, 0, stream>>>(emb, efrag, e2b, loss);
    rvq_fused<<<NROWS/64, 256, 0, stream>>>(x, out, emb, efrag, e2b, idx_base, loss);
    rvq_loss<<<1, 1, 0, stream>>>(loss, loss_out);
}